// Round 5
// baseline (521.772 us; speedup 1.0000x reference)
//
#include <hip/hip_runtime.h>
#include <math.h>

#define EPSF 1e-5f

// ---- problem dims ----
#define NROW   32768   // B*H*W image tokens
#define CDIM   384
#define N3     1152
#define FFDIM  1536

typedef unsigned short ushort_t;
typedef __attribute__((ext_vector_type(8))) short short8v;   // 8 bf16 (4 VGPRs)
typedef __attribute__((ext_vector_type(4))) float f32x4;     // MFMA accumulator

__device__ __forceinline__ float gelu_exact(float v) {
    return 0.5f * v * (1.f + erff(v * 0.70710678118654752f));
}

// fp32 -> bf16 round-to-nearest-even
__device__ __forceinline__ ushort_t f2bf(float f) {
    union { float f; unsigned u; } v; v.f = f;
    unsigned r = v.u + 0x7fffu + ((v.u >> 16) & 1u);
    return (ushort_t)(r >> 16);
}

// async global->LDS, 16B per lane; LDS dest is wave-uniform base + lane*16
__device__ __forceinline__ void gload_lds16(const void* g, void* l) {
    __builtin_amdgcn_global_load_lds(
        (const __attribute__((address_space(1))) void*)g,
        (__attribute__((address_space(3))) void*)l, 16, 0, 0);
}

// ---------------- weight transpose + bf16 convert: W[K][N] -> Wt[N][K] ----------------
__global__ __launch_bounds__(256) void wt_bf16_kernel(const float* __restrict__ W,
                                                      ushort_t* __restrict__ Wt,
                                                      int K, int N) {
    __shared__ float t[32][33];
    const int bx = blockIdx.x, by = blockIdx.y;       // n-tile, k-tile
    const int c = threadIdx.x & 31, r0 = threadIdx.x >> 5;
    #pragma unroll
    for (int i = 0; i < 4; ++i) {
        int r = r0 + i * 8;
        t[r][c] = W[(size_t)(by * 32 + r) * N + bx * 32 + c];
    }
    __syncthreads();
    #pragma unroll
    for (int i = 0; i < 4; ++i) {
        int r = r0 + i * 8;
        Wt[(size_t)(bx * 32 + r) * K + by * 32 + c] = f2bf(t[c][r]);
    }
}

// ---------------- padvec: qkv row of a zero-padded token (bf16 out) ----------------
__global__ __launch_bounds__(256) void padvec_kernel(
    const float* __restrict__ ln1_b, const float* __restrict__ qkv_w,
    const float* __restrict__ qkv_b, ushort_t* __restrict__ padvec)
{
    int j = blockIdx.x * 256 + threadIdx.x;
    if (j >= N3) return;
    float acc = qkv_b[j];
    for (int k = 0; k < CDIM; ++k) acc = fmaf(ln1_b[k], qkv_w[k * N3 + j], acc);
    padvec[j] = f2bf(acc);
}

// ---------------- fused LN (stats + normalize) -> bf16 rows, one wave/row ----------------
__global__ __launch_bounds__(256) void ln_bf16_kernel(
    const float* __restrict__ src, const float* __restrict__ w,
    const float* __restrict__ b, ushort_t* __restrict__ dst)
{
    const int row  = blockIdx.x * 4 + (threadIdx.x >> 6);
    const int lane = threadIdx.x & 63;
    const float* p = src + (size_t)row * CDIM;
    float vals[6];
    float s1 = 0.f, s2 = 0.f;
    #pragma unroll
    for (int i = 0; i < 6; ++i) {
        float v = p[lane + 64 * i];
        vals[i] = v; s1 += v; s2 += v * v;
    }
    #pragma unroll
    for (int off = 32; off > 0; off >>= 1) {
        s1 += __shfl_xor(s1, off);
        s2 += __shfl_xor(s2, off);
    }
    float mu = s1 * (1.f / CDIM);
    float rs = rsqrtf(s2 * (1.f / CDIM) - mu * mu + EPSF);
    ushort_t* q = dst + (size_t)row * CDIM;
    #pragma unroll
    for (int i = 0; i < 6; ++i) {
        int k = lane + 64 * i;
        q[k] = f2bf((vals[i] - mu) * rs * w[k] + b[k]);
    }
}

// ---------------- bf16 MFMA GEMM (m97 structure): C = A[M][K] @ Bt[N][K]^T ----------------
// 128x128 tile, BK=64, 4 waves (64x64 each), global_load_lds staging (linear LDS),
// XCD-chunked block swizzle, LDS-repacked coalesced epilogue.
// EPI: 0 = +bias, bf16 store (qkv)
//      1 = +bias, gelu, bf16 store (fc1)
//      2 = +bias, +resid, fp32 store (proj, fc2)
template<int EPI>
__global__ __launch_bounds__(256) void gemm_bf16_kernel(
    const ushort_t* __restrict__ A, const ushort_t* __restrict__ Bt,
    const float* __restrict__ bias, void* __restrict__ outv,
    const float* __restrict__ resid, int Nn, int K)
{
    // staging (32 KB) and per-wave C-repack (34 KB) share one allocation
    __shared__ __align__(16) char raw[34816];
    ushort_t (*As)[64] = (ushort_t(*)[64])raw;            // [128][64]
    ushort_t (*Bs)[64] = (ushort_t(*)[64])(raw + 16384);  // [128][64]

    const int tid  = threadIdx.x;
    const int lane = tid & 63;
    const int wv   = tid >> 6;
    const int wm   = (wv & 1) * 64, wn = (wv >> 1) * 64;

    // T1: bijective chunked XCD swizzle (nwg % 8 == 0 for all our grids)
    const int nbx = gridDim.x;
    const int nwg = nbx * gridDim.y;
    const int id  = blockIdx.y * nbx + blockIdx.x;
    const int cpx = nwg >> 3;
    const int swz = (id & 7) * cpx + (id >> 3);
    const int bn0 = (swz % nbx) * 128;
    const int bm0 = (swz / nbx) * 128;

    // staging: each wave fills rows [wv*32, wv*32+32), 8 rows per gload_lds
    const int g_row = lane >> 3;        // 0..7
    const int g_col = (lane & 7) * 8;   // bf16 col within 64-tile

    f32x4 acc[4][4] = {};

    const int cl = lane & 15;
    const int lg = lane >> 4;
    const int kq = lg * 8;

    for (int kt = 0; kt < K; kt += 64) {
        if (kt) __syncthreads();
        #pragma unroll
        for (int i = 0; i < 4; ++i) {
            const int r = wv * 32 + i * 8;
            gload_lds16(A  + (size_t)(bm0 + r + g_row) * K + kt + g_col, &As[r][0]);
            gload_lds16(Bt + (size_t)(bn0 + r + g_row) * K + kt + g_col, &Bs[r][0]);
        }
        __syncthreads();
        #pragma unroll
        for (int kb = 0; kb < 2; ++kb) {
            const int ko = kb * 32 + kq;
            short8v a[4], b[4];
            #pragma unroll
            for (int mi = 0; mi < 4; ++mi)
                a[mi] = *(const short8v*)&As[wm + mi * 16 + cl][ko];
            #pragma unroll
            for (int ni = 0; ni < 4; ++ni)
                b[ni] = *(const short8v*)&Bs[wn + ni * 16 + cl][ko];
            #pragma unroll
            for (int mi = 0; mi < 4; ++mi)
                #pragma unroll
                for (int ni = 0; ni < 4; ++ni)
                    acc[mi][ni] = __builtin_amdgcn_mfma_f32_16x16x32_bf16(
                        a[mi], b[ni], acc[mi][ni], 0, 0, 0);
        }
    }
    __syncthreads();   // staging LDS dead; reuse as C-repack buffer

    // ---- epilogue: repack through LDS, coalesced stores ----
    float* Cw = (float*)(raw + wv * 8704);   // per-wave [32][68] fp32
    const int ecol = cl * 4;                  // this lane's 4 output cols
    const float4 bb = *(const float4*)(bias + bn0 + wn + ecol);

    #pragma unroll
    for (int half = 0; half < 2; ++half) {
        // write phase: 2 mi-blocks -> [32][68]
        #pragma unroll
        for (int mi2 = 0; mi2 < 2; ++mi2) {
            #pragma unroll
            for (int ni = 0; ni < 4; ++ni) {
                #pragma unroll
                for (int r = 0; r < 4; ++r)
                    Cw[(mi2 * 16 + lg * 4 + r) * 68 + ni * 16 + cl] =
                        acc[half * 2 + mi2][ni][r];
            }
        }
        __syncthreads();
        // read/store phase: row-major, 64 contiguous cols per 16-lane group
        #pragma unroll
        for (int i = 0; i < 8; ++i) {
            const int lrow = i * 4 + lg;
            const int grow = bm0 + wm + half * 32 + lrow;
            float4 v = *(const float4*)&Cw[lrow * 68 + ecol];
            v.x += bb.x; v.y += bb.y; v.z += bb.z; v.w += bb.w;
            size_t off = (size_t)grow * Nn + bn0 + wn + ecol;
            if (EPI == 0) {
                ushort4 pk = { f2bf(v.x), f2bf(v.y), f2bf(v.z), f2bf(v.w) };
                *(ushort4*)((ushort_t*)outv + off) = pk;
            } else if (EPI == 1) {
                ushort4 pk = { f2bf(gelu_exact(v.x)), f2bf(gelu_exact(v.y)),
                               f2bf(gelu_exact(v.z)), f2bf(gelu_exact(v.w)) };
                *(ushort4*)((ushort_t*)outv + off) = pk;
            } else {
                float4 r0 = *(const float4*)(resid + off);
                v.x += r0.x; v.y += r0.y; v.z += r0.z; v.w += r0.w;
                *(float4*)((float*)outv + off) = v;
            }
        }
        __syncthreads();
    }
}

// ---------------- MFMA window attention: one block per (window, head) ----------------
__global__ __launch_bounds__(256) void attn_kernel(
    const ushort_t* __restrict__ qkv, const ushort_t* __restrict__ padvec,
    const float* __restrict__ attn_bias, const int* __restrict__ bias_idxs,
    ushort_t* __restrict__ o)
{
    const int w = blockIdx.x / 12;     // window 0..799
    const int h = blockIdx.x % 12;     // head
    __shared__ ushort_t Qs[64][40];    // [token][d], 80B stride
    __shared__ ushort_t Ks[64][40];
    __shared__ ushort_t Vts[32][72];   // [d][token], 144B stride
    __shared__ ushort_t Ps[64][72];    // [query][key]
    __shared__ float    browl[49];
    __shared__ int      simgl[49];
    const int tid  = threadIdx.x;
    const int lane = tid & 63;
    const int wv   = tid >> 6;
    const int cl   = lane & 15;
    const int lg   = lane >> 4;

    if (tid < 49) {
        int b  = w / 25, wi = w % 25;
        int gh = (wi / 5) * 7 + tid / 7;
        int gw = (wi % 5) * 7 + tid % 7;
        simgl[tid] = (gh < 32 && gw < 32) ? (b * 1024 + gh * 32 + gw) : -1;
        browl[tid] = attn_bias[h * 49 + tid];
    }

    // stage Q,K ([token][d]) and V transposed ([d][token]); t>=49 zeroed
    for (int e = tid; e < 64 * 12; e += 256) {
        int t = e / 12, j = e % 12;
        uint4 val = make_uint4(0u, 0u, 0u, 0u);
        if (t < 49) {
            int b  = w / 25, wi = w % 25;
            int gh = (wi / 5) * 7 + t / 7;
            int gw = (wi % 5) * 7 + t % 7;
            const ushort_t* src = (gh < 32 && gw < 32)
                ? qkv + (size_t)(b * 1024 + gh * 32 + gw) * N3 + h * 96 + j * 8
                : padvec + h * 96 + j * 8;
            val = *(const uint4*)src;
        }
        if (j < 4)      *(uint4*)&Qs[t][j * 8] = val;
        else if (j < 8) *(uint4*)&Ks[t][(j - 4) * 8] = val;
        else {
            int d0 = (j - 8) * 8;
            unsigned uu[4] = {val.x, val.y, val.z, val.w};
            #pragma unroll
            for (int ii = 0; ii < 4; ++ii) {
                Vts[d0 + 2 * ii + 0][t] = (ushort_t)(uu[ii] & 0xffffu);
                Vts[d0 + 2 * ii + 1][t] = (ushort_t)(uu[ii] >> 16);
            }
        }
    }
    __syncthreads();

    // ---- S^T = K @ Q^T ----
    const int q = wv * 16 + cl;
    short8v qf = *(const short8v*)&Qs[q][lg * 8];
    f32x4 st[4];
    #pragma unroll
    for (int mi = 0; mi < 4; ++mi) {
        short8v kf = *(const short8v*)&Ks[mi * 16 + cl][lg * 8];
        f32x4 z = {};
        st[mi] = __builtin_amdgcn_mfma_f32_16x16x32_bf16(kf, qf, z, 0, 0, 0);
    }

    // ---- bias + in-register softmax over keys ----
    float sv[4][4];
    float m = -1e30f;
    #pragma unroll
    for (int mi = 0; mi < 4; ++mi)
        #pragma unroll
        for (int r = 0; r < 4; ++r) {
            int key = mi * 16 + lg * 4 + r;
            float bb = (q < 49 && key < 49)
                     ? browl[bias_idxs[q * 49 + key]] : -1e30f;
            float s = st[mi][r] * 0.17677669529663687f + bb;
            sv[mi][r] = s;
            m = fmaxf(m, s);
        }
    m = fmaxf(m, __shfl_xor(m, 16));
    m = fmaxf(m, __shfl_xor(m, 32));
    float sum = 0.f;
    #pragma unroll
    for (int mi = 0; mi < 4; ++mi)
        #pragma unroll
        for (int r = 0; r < 4; ++r) {
            float p = __expf(sv[mi][r] - m);
            sv[mi][r] = p;
            sum += p;
        }
    sum += __shfl_xor(sum, 16);
    sum += __shfl_xor(sum, 32);
    const float inv = 1.f / sum;

    // ---- P -> LDS (wave-local rows; no barrier) ----
    #pragma unroll
    for (int mi = 0; mi < 4; ++mi) {
        uint2 pk;
        pk.x = (unsigned)f2bf(sv[mi][0] * inv) | ((unsigned)f2bf(sv[mi][1] * inv) << 16);
        pk.y = (unsigned)f2bf(sv[mi][2] * inv) | ((unsigned)f2bf(sv[mi][3] * inv) << 16);
        *(uint2*)&Ps[q][mi * 16 + lg * 4] = pk;
    }

    // ---- O = P @ V ----
    f32x4 oacc[2] = {};
    #pragma unroll
    for (int kb = 0; kb < 2; ++kb) {
        short8v pa = *(const short8v*)&Ps[q][kb * 32 + lg * 8];
        #pragma unroll
        for (int ni = 0; ni < 2; ++ni) {
            short8v vb = *(const short8v*)&Vts[ni * 16 + cl][kb * 32 + lg * 8];
            oacc[ni] = __builtin_amdgcn_mfma_f32_16x16x32_bf16(pa, vb, oacc[ni], 0, 0, 0);
        }
    }

    // ---- scatter ----
    #pragma unroll
    for (int ni = 0; ni < 2; ++ni) {
        int d = h * 32 + ni * 16 + cl;
        #pragma unroll
        for (int r = 0; r < 4; ++r) {
            int q2 = wv * 16 + lg * 4 + r;
            if (q2 < 49) {
                int si = simgl[q2];
                if (si >= 0) o[(size_t)si * CDIM + d] = f2bf(oacc[ni][r]);
            }
        }
    }
}

// ---------------- depthwise 3x3 conv (channels-last) + BN (fp32) ----------------
__global__ __launch_bounds__(256) void conv_bn_kernel(
    const float* __restrict__ xin, const float* __restrict__ cw,
    const float* __restrict__ bn_g, const float* __restrict__ bn_b,
    const float* __restrict__ bn_m, const float* __restrict__ bn_v,
    float* __restrict__ xout)
{
    __shared__ float wsm[9 * 384];
    for (int i = threadIdx.x; i < 9 * 384; i += 256) {
        int c = i / 9, wi = i % 9;
        wsm[wi * 384 + c] = cw[i];
    }
    __syncthreads();

    int gid = blockIdx.x * 256 + threadIdx.x;
    int c4 = gid % 96;
    int t  = gid / 96;
    int w  = t % 32; t /= 32;
    int h  = t % 32;
    int b  = t / 32;
    int c0 = c4 * 4;

    float4 acc = make_float4(0.f, 0.f, 0.f, 0.f);
    #pragma unroll
    for (int dh = -1; dh <= 1; ++dh) {
        int hh = h + dh;
        if (hh < 0 || hh >= 32) continue;
        #pragma unroll
        for (int dw = -1; dw <= 1; ++dw) {
            int ww = w + dw;
            if (ww < 0 || ww >= 32) continue;
            float4 xv = *(const float4*)(xin + ((size_t)(b * 1024 + hh * 32 + ww)) * CDIM + c0);
            float4 wv = *(const float4*)&wsm[((dh + 1) * 3 + (dw + 1)) * 384 + c0];
            acc.x = fmaf(xv.x, wv.x, acc.x);
            acc.y = fmaf(xv.y, wv.y, acc.y);
            acc.z = fmaf(xv.z, wv.z, acc.z);
            acc.w = fmaf(xv.w, wv.w, acc.w);
        }
    }
    float4 o;
    float sc;
    sc = rsqrtf(bn_v[c0 + 0] + EPSF) * bn_g[c0 + 0]; o.x = (acc.x - bn_m[c0 + 0]) * sc + bn_b[c0 + 0];
    sc = rsqrtf(bn_v[c0 + 1] + EPSF) * bn_g[c0 + 1]; o.y = (acc.y - bn_m[c0 + 1]) * sc + bn_b[c0 + 1];
    sc = rsqrtf(bn_v[c0 + 2] + EPSF) * bn_g[c0 + 2]; o.z = (acc.z - bn_m[c0 + 2]) * sc + bn_b[c0 + 2];
    sc = rsqrtf(bn_v[c0 + 3] + EPSF) * bn_g[c0 + 3]; o.w = (acc.w - bn_m[c0 + 3]) * sc + bn_b[c0 + 3];
    *(float4*)(xout + (size_t)gid * 4) = o;
}

// ---------------- launch ----------------
extern "C" void kernel_launch(void* const* d_in, const int* in_sizes, int n_in,
                              void* d_out, int out_size, void* d_ws, size_t ws_size,
                              hipStream_t stream) {
    const float* x         = (const float*)d_in[0];
    const float* ln1_w     = (const float*)d_in[1];
    const float* ln1_b     = (const float*)d_in[2];
    const float* qkv_w     = (const float*)d_in[3];
    const float* qkv_b     = (const float*)d_in[4];
    const float* proj_w    = (const float*)d_in[5];
    const float* proj_b    = (const float*)d_in[6];
    const float* attn_bias = (const float*)d_in[7];
    const int*   bias_idxs = (const int*)d_in[8];
    const float* conv_w    = (const float*)d_in[9];
    const float* bn_g      = (const float*)d_in[10];
    const float* bn_b      = (const float*)d_in[11];
    const float* bn_m      = (const float*)d_in[12];
    const float* bn_v      = (const float*)d_in[13];
    const float* ln2_w     = (const float*)d_in[14];
    const float* ln2_b     = (const float*)d_in[15];
    const float* fc1_w     = (const float*)d_in[16];
    const float* fc1_b     = (const float*)d_in[17];
    const float* fc2_w     = (const float*)d_in[18];
    const float* fc2_b     = (const float*)d_in[19];
    float* out = (float*)d_out;

    // workspace with lifetime overlays (see round-3 comment)
    char* ws = (char*)d_ws;
    ushort_t* A1    = (ushort_t*)(ws + 0);              // 32768*384*2  = 25,165,824
    ushort_t* oimg  = (ushort_t*)(ws + 0);
    ushort_t* A2    = (ushort_t*)(ws + 0);
    ushort_t* qkvb  = (ushort_t*)(ws + 25165824ULL);    // 32768*1152*2 = 75,497,472
    float*    x1    = (float*)(ws + 25165824ULL);       // 32768*384*4
    ushort_t* hbuf  = (ushort_t*)(ws + 25165824ULL);    // 32768*1536*2 = 100,663,296
    ushort_t* wtqkv = (ushort_t*)(ws + 176160768ULL);   // 1152*384*2 = 884,736
    ushort_t* wtprj = (ushort_t*)(ws + 177045504ULL);   // 384*384*2  = 294,912
    ushort_t* wtfc1 = (ushort_t*)(ws + 177340416ULL);   // 1536*384*2 = 1,179,648
    ushort_t* wtfc2 = (ushort_t*)(ws + 178520064ULL);   // 384*1536*2 = 1,179,648
    ushort_t* pvec  = (ushort_t*)(ws + 179699712ULL);   // 2,304

    // 0) weights -> bf16 [N][K]
    wt_bf16_kernel<<<dim3(36, 12), 256, 0, stream>>>(qkv_w,  wtqkv, 384, 1152);
    wt_bf16_kernel<<<dim3(12, 12), 256, 0, stream>>>(proj_w, wtprj, 384, 384);
    wt_bf16_kernel<<<dim3(48, 12), 256, 0, stream>>>(fc1_w,  wtfc1, 384, 1536);
    wt_bf16_kernel<<<dim3(12, 48), 256, 0, stream>>>(fc2_w,  wtfc2, 1536, 384);
    // 1) pad-slot qkv row (bf16)
    padvec_kernel<<<5, 256, 0, stream>>>(ln1_b, qkv_w, qkv_b, pvec);
    // 2) A1 = bf16(LN1(x))
    ln_bf16_kernel<<<8192, 256, 0, stream>>>(x, ln1_w, ln1_b, A1);
    // 3) qkvb = A1 @ wtqkv^T + qkv_b (bf16 out)   nwg=2304
    gemm_bf16_kernel<0><<<dim3(9, 256), 256, 0, stream>>>(
        A1, wtqkv, qkv_b, qkvb, nullptr, N3, CDIM);
    // 4) MFMA windowed attention -> oimg bf16
    attn_kernel<<<9600, 256, 0, stream>>>(qkvb, pvec, attn_bias, bias_idxs, oimg);
    // 5) x1 = x + oimg @ wtprj^T + proj_b   nwg=768
    gemm_bf16_kernel<2><<<dim3(3, 256), 256, 0, stream>>>(
        oimg, wtprj, proj_b, x1, x, CDIM, CDIM);
    // 6) x2(=d_out) = BN(dwconv3x3(x1))
    conv_bn_kernel<<<12288, 256, 0, stream>>>(x1, conv_w, bn_g, bn_b, bn_m, bn_v, out);
    // 7) A2 = bf16(LN2(x2))
    ln_bf16_kernel<<<8192, 256, 0, stream>>>(out, ln2_w, ln2_b, A2);
    // 8) hbuf = bf16(gelu(A2 @ wtfc1^T + fc1_b))   nwg=3072
    gemm_bf16_kernel<1><<<dim3(12, 256), 256, 0, stream>>>(
        A2, wtfc1, fc1_b, hbuf, nullptr, FFDIM, CDIM);
    // 9) out = x2 + hbuf @ wtfc2^T + fc2_b  (in place over d_out)   nwg=768
    gemm_bf16_kernel<2><<<dim3(3, 256), 256, 0, stream>>>(
        hbuf, wtfc2, fc2_b, out, out, CDIM, FFDIM);
}

// Round 6
// 452.948 us; speedup vs baseline: 1.1519x; 1.1519x over previous
//
#include <hip/hip_runtime.h>
#include <math.h>

#define EPSF 1e-5f

// ---- problem dims ----
#define NROW   32768   // B*H*W image tokens
#define CDIM   384
#define N3     1152
#define FFDIM  1536

typedef unsigned short ushort_t;
typedef __attribute__((ext_vector_type(8))) short short8v;   // 8 bf16 (4 VGPRs)
typedef __attribute__((ext_vector_type(4))) float f32x4;     // MFMA accumulator

__device__ __forceinline__ float gelu_exact(float v) {
    return 0.5f * v * (1.f + erff(v * 0.70710678118654752f));
}

// branchless tanh-form GELU: x*sigmoid(1.5957691*(x+0.044715x^3)).
// max |err| vs exact-erf gelu ~5e-4 — below the bf16 ulp (~0.008) the output
// is quantized to anyway.
__device__ __forceinline__ float gelu_fast(float x) {
    float y = 1.5957691216f * x + 0.0713548162f * (x * x * x);
    return x * __builtin_amdgcn_rcpf(1.f + __expf(-y));
}

// fp32 -> bf16 round-to-nearest-even
__device__ __forceinline__ ushort_t f2bf(float f) {
    union { float f; unsigned u; } v; v.f = f;
    unsigned r = v.u + 0x7fffu + ((v.u >> 16) & 1u);
    return (ushort_t)(r >> 16);
}

// async global->LDS, 16B per lane; LDS dest is wave-uniform base + lane*16
__device__ __forceinline__ void gload_lds16(const void* g, void* l) {
    __builtin_amdgcn_global_load_lds(
        (const __attribute__((address_space(1))) void*)g,
        (__attribute__((address_space(3))) void*)l, 16, 0, 0);
}

// ---------------- weight transpose + bf16 convert: W[K][N] -> Wt[N][K] ----------------
__global__ __launch_bounds__(256) void wt_bf16_kernel(const float* __restrict__ W,
                                                      ushort_t* __restrict__ Wt,
                                                      int K, int N) {
    __shared__ float t[32][33];
    const int bx = blockIdx.x, by = blockIdx.y;       // n-tile, k-tile
    const int c = threadIdx.x & 31, r0 = threadIdx.x >> 5;
    #pragma unroll
    for (int i = 0; i < 4; ++i) {
        int r = r0 + i * 8;
        t[r][c] = W[(size_t)(by * 32 + r) * N + bx * 32 + c];
    }
    __syncthreads();
    #pragma unroll
    for (int i = 0; i < 4; ++i) {
        int r = r0 + i * 8;
        Wt[(size_t)(bx * 32 + r) * K + by * 32 + c] = f2bf(t[c][r]);
    }
}

// ---------------- padvec: qkv row of a zero-padded token (bf16 out) ----------------
__global__ __launch_bounds__(256) void padvec_kernel(
    const float* __restrict__ ln1_b, const float* __restrict__ qkv_w,
    const float* __restrict__ qkv_b, ushort_t* __restrict__ padvec)
{
    int j = blockIdx.x * 256 + threadIdx.x;
    if (j >= N3) return;
    float acc = qkv_b[j];
    for (int k = 0; k < CDIM; ++k) acc = fmaf(ln1_b[k], qkv_w[k * N3 + j], acc);
    padvec[j] = f2bf(acc);
}

// ---------------- fused LN (stats + normalize) -> bf16 rows, one wave/row ----------------
__global__ __launch_bounds__(256) void ln_bf16_kernel(
    const float* __restrict__ src, const float* __restrict__ w,
    const float* __restrict__ b, ushort_t* __restrict__ dst)
{
    const int row  = blockIdx.x * 4 + (threadIdx.x >> 6);
    const int lane = threadIdx.x & 63;
    const float* p = src + (size_t)row * CDIM;
    float vals[6];
    float s1 = 0.f, s2 = 0.f;
    #pragma unroll
    for (int i = 0; i < 6; ++i) {
        float v = p[lane + 64 * i];
        vals[i] = v; s1 += v; s2 += v * v;
    }
    #pragma unroll
    for (int off = 32; off > 0; off >>= 1) {
        s1 += __shfl_xor(s1, off);
        s2 += __shfl_xor(s2, off);
    }
    float mu = s1 * (1.f / CDIM);
    float rs = rsqrtf(s2 * (1.f / CDIM) - mu * mu + EPSF);
    ushort_t* q = dst + (size_t)row * CDIM;
    #pragma unroll
    for (int i = 0; i < 6; ++i) {
        int k = lane + 64 * i;
        q[k] = f2bf((vals[i] - mu) * rs * w[k] + b[k]);
    }
}

// ---------------- bf16 MFMA GEMM (m97 structure + swizzled LDS): ----------------
// C = A[M][K] @ Bt[N][K]^T. 128x128 tile, BK=64, 4 waves, global_load_lds staging
// with PRE-SWIZZLED global source (rule 21: linear LDS dest + inverse-swz source +
// matching XOR on ds_read -> 16-way bank conflict becomes free 2-way).
// EPI: 0 = +bias, bf16 store (qkv)
//      1 = +bias, gelu, bf16 store (fc1)
//      2 = +bias, +resid, fp32 store (proj, fc2)
template<int EPI>
__global__ __launch_bounds__(256) void gemm_bf16_kernel(
    const ushort_t* __restrict__ A, const ushort_t* __restrict__ Bt,
    const float* __restrict__ bias, void* __restrict__ outv,
    const float* __restrict__ resid, int Nn, int K)
{
    // staging (32 KB) and per-wave C-repack (34 KB) share one allocation
    __shared__ __align__(16) char raw[34816];
    ushort_t (*As)[64] = (ushort_t(*)[64])raw;            // [128][64] linear dest
    ushort_t (*Bs)[64] = (ushort_t(*)[64])(raw + 16384);  // [128][64]

    const int tid  = threadIdx.x;
    const int lane = tid & 63;
    const int wv   = tid >> 6;
    const int wm   = (wv & 1) * 64, wn = (wv >> 1) * 64;

    // T1: bijective chunked XCD swizzle (nwg % 8 == 0 for all our grids)
    const int nbx = gridDim.x;
    const int nwg = nbx * gridDim.y;
    const int id  = blockIdx.y * nbx + blockIdx.x;
    const int cpx = nwg >> 3;
    const int swz = (id & 7) * cpx + (id >> 3);
    const int bn0 = (swz % nbx) * 128;
    const int bm0 = (swz / nbx) * 128;

    // staging: wave fills rows [wv*32, +32), 8 rows per gload_lds.
    // source column is inverse-swizzled so that swizzled reads see the
    // right data: lane l covers row (l>>3), chunk ((l&7) ^ (l>>3)).
    const int g_row = lane >> 3;                       // 0..7
    const int g_col = ((lane & 7) ^ g_row) * 8;        // element col (8 bf16/chunk)

    f32x4 acc[4][4] = {};

    const int cl = lane & 15;
    const int lg = lane >> 4;
    const int sx = (cl & 7) << 4;                      // read-side byte XOR

    const char* Ab = raw;
    const char* Bb = raw + 16384;

    for (int kt = 0; kt < K; kt += 64) {
        if (kt) __syncthreads();
        #pragma unroll
        for (int i = 0; i < 4; ++i) {
            const int r = wv * 32 + i * 8;
            gload_lds16(A  + (size_t)(bm0 + r + g_row) * K + kt + g_col, &As[r][0]);
            gload_lds16(Bt + (size_t)(bn0 + r + g_row) * K + kt + g_col, &Bs[r][0]);
        }
        __syncthreads();
        #pragma unroll
        for (int kb = 0; kb < 2; ++kb) {
            const int cob = (kb * 64 + lg * 16) ^ sx;  // swizzled byte col
            short8v a[4], b[4];
            #pragma unroll
            for (int mi = 0; mi < 4; ++mi)
                a[mi] = *(const short8v*)(Ab + (wm + mi * 16 + cl) * 128 + cob);
            #pragma unroll
            for (int ni = 0; ni < 4; ++ni)
                b[ni] = *(const short8v*)(Bb + (wn + ni * 16 + cl) * 128 + cob);
            #pragma unroll
            for (int mi = 0; mi < 4; ++mi)
                #pragma unroll
                for (int ni = 0; ni < 4; ++ni)
                    acc[mi][ni] = __builtin_amdgcn_mfma_f32_16x16x32_bf16(
                        a[mi], b[ni], acc[mi][ni], 0, 0, 0);
        }
    }
    __syncthreads();   // staging LDS dead; reuse as C-repack buffer

    // ---- epilogue: repack through LDS, coalesced stores ----
    float* Cw = (float*)(raw + wv * 8704);   // per-wave [32][68] fp32
    const int ecol = cl * 4;                  // this lane's 4 output cols
    const float4 bb = *(const float4*)(bias + bn0 + wn + ecol);

    #pragma unroll
    for (int half = 0; half < 2; ++half) {
        // write phase: 2 mi-blocks -> [32][68]
        #pragma unroll
        for (int mi2 = 0; mi2 < 2; ++mi2) {
            #pragma unroll
            for (int ni = 0; ni < 4; ++ni) {
                #pragma unroll
                for (int r = 0; r < 4; ++r)
                    Cw[(mi2 * 16 + lg * 4 + r) * 68 + ni * 16 + cl] =
                        acc[half * 2 + mi2][ni][r];
            }
        }
        __syncthreads();
        // read/store phase: row-major, 64 contiguous cols per 16-lane group
        #pragma unroll
        for (int i = 0; i < 8; ++i) {
            const int lrow = i * 4 + lg;
            const int grow = bm0 + wm + half * 32 + lrow;
            float4 v = *(const float4*)&Cw[lrow * 68 + ecol];
            v.x += bb.x; v.y += bb.y; v.z += bb.z; v.w += bb.w;
            size_t off = (size_t)grow * Nn + bn0 + wn + ecol;
            if (EPI == 0) {
                ushort4 pk = { f2bf(v.x), f2bf(v.y), f2bf(v.z), f2bf(v.w) };
                *(ushort4*)((ushort_t*)outv + off) = pk;
            } else if (EPI == 1) {
                ushort4 pk = { f2bf(gelu_fast(v.x)), f2bf(gelu_fast(v.y)),
                               f2bf(gelu_fast(v.z)), f2bf(gelu_fast(v.w)) };
                *(ushort4*)((ushort_t*)outv + off) = pk;
            } else {
                float4 r0 = *(const float4*)(resid + off);
                v.x += r0.x; v.y += r0.y; v.z += r0.z; v.w += r0.w;
                *(float4*)((float*)outv + off) = v;
            }
        }
        __syncthreads();
    }
}

// ---------------- MFMA window attention: one block per (window, head) ----------------
__global__ __launch_bounds__(256) void attn_kernel(
    const ushort_t* __restrict__ qkv, const ushort_t* __restrict__ padvec,
    const float* __restrict__ attn_bias, const int* __restrict__ bias_idxs,
    ushort_t* __restrict__ o)
{
    const int w = blockIdx.x / 12;     // window 0..799
    const int h = blockIdx.x % 12;     // head
    __shared__ ushort_t Qs[64][40];    // [token][d], 80B stride
    __shared__ ushort_t Ks[64][40];
    __shared__ ushort_t Vts[32][72];   // [d][token], 144B stride
    __shared__ ushort_t Ps[64][72];    // [query][key]
    __shared__ float    browl[49];
    __shared__ int      simgl[49];
    const int tid  = threadIdx.x;
    const int lane = tid & 63;
    const int wv   = tid >> 6;
    const int cl   = lane & 15;
    const int lg   = lane >> 4;

    if (tid < 49) {
        int b  = w / 25, wi = w % 25;
        int gh = (wi / 5) * 7 + tid / 7;
        int gw = (wi % 5) * 7 + tid % 7;
        simgl[tid] = (gh < 32 && gw < 32) ? (b * 1024 + gh * 32 + gw) : -1;
        browl[tid] = attn_bias[h * 49 + tid];
    }

    // stage Q,K ([token][d]) and V transposed ([d][token]); t>=49 zeroed
    for (int e = tid; e < 64 * 12; e += 256) {
        int t = e / 12, j = e % 12;
        uint4 val = make_uint4(0u, 0u, 0u, 0u);
        if (t < 49) {
            int b  = w / 25, wi = w % 25;
            int gh = (wi / 5) * 7 + t / 7;
            int gw = (wi % 5) * 7 + t % 7;
            const ushort_t* src = (gh < 32 && gw < 32)
                ? qkv + (size_t)(b * 1024 + gh * 32 + gw) * N3 + h * 96 + j * 8
                : padvec + h * 96 + j * 8;
            val = *(const uint4*)src;
        }
        if (j < 4)      *(uint4*)&Qs[t][j * 8] = val;
        else if (j < 8) *(uint4*)&Ks[t][(j - 4) * 8] = val;
        else {
            int d0 = (j - 8) * 8;
            unsigned uu[4] = {val.x, val.y, val.z, val.w};
            #pragma unroll
            for (int ii = 0; ii < 4; ++ii) {
                Vts[d0 + 2 * ii + 0][t] = (ushort_t)(uu[ii] & 0xffffu);
                Vts[d0 + 2 * ii + 1][t] = (ushort_t)(uu[ii] >> 16);
            }
        }
    }
    __syncthreads();

    // ---- S^T = K @ Q^T ----
    const int q = wv * 16 + cl;
    short8v qf = *(const short8v*)&Qs[q][lg * 8];
    f32x4 st[4];
    #pragma unroll
    for (int mi = 0; mi < 4; ++mi) {
        short8v kf = *(const short8v*)&Ks[mi * 16 + cl][lg * 8];
        f32x4 z = {};
        st[mi] = __builtin_amdgcn_mfma_f32_16x16x32_bf16(kf, qf, z, 0, 0, 0);
    }

    // ---- bias + in-register softmax over keys ----
    float sv[4][4];
    float m = -1e30f;
    #pragma unroll
    for (int mi = 0; mi < 4; ++mi)
        #pragma unroll
        for (int r = 0; r < 4; ++r) {
            int key = mi * 16 + lg * 4 + r;
            float bb = (q < 49 && key < 49)
                     ? browl[bias_idxs[q * 49 + key]] : -1e30f;
            float s = st[mi][r] * 0.17677669529663687f + bb;
            sv[mi][r] = s;
            m = fmaxf(m, s);
        }
    m = fmaxf(m, __shfl_xor(m, 16));
    m = fmaxf(m, __shfl_xor(m, 32));
    float sum = 0.f;
    #pragma unroll
    for (int mi = 0; mi < 4; ++mi)
        #pragma unroll
        for (int r = 0; r < 4; ++r) {
            float p = __expf(sv[mi][r] - m);
            sv[mi][r] = p;
            sum += p;
        }
    sum += __shfl_xor(sum, 16);
    sum += __shfl_xor(sum, 32);
    const float inv = 1.f / sum;

    // ---- P -> LDS (wave-local rows; no barrier) ----
    #pragma unroll
    for (int mi = 0; mi < 4; ++mi) {
        uint2 pk;
        pk.x = (unsigned)f2bf(sv[mi][0] * inv) | ((unsigned)f2bf(sv[mi][1] * inv) << 16);
        pk.y = (unsigned)f2bf(sv[mi][2] * inv) | ((unsigned)f2bf(sv[mi][3] * inv) << 16);
        *(uint2*)&Ps[q][mi * 16 + lg * 4] = pk;
    }

    // ---- O = P @ V ----
    f32x4 oacc[2] = {};
    #pragma unroll
    for (int kb = 0; kb < 2; ++kb) {
        short8v pa = *(const short8v*)&Ps[q][kb * 32 + lg * 8];
        #pragma unroll
        for (int ni = 0; ni < 2; ++ni) {
            short8v vb = *(const short8v*)&Vts[ni * 16 + cl][kb * 32 + lg * 8];
            oacc[ni] = __builtin_amdgcn_mfma_f32_16x16x32_bf16(pa, vb, oacc[ni], 0, 0, 0);
        }
    }

    // ---- scatter ----
    #pragma unroll
    for (int ni = 0; ni < 2; ++ni) {
        int d = h * 32 + ni * 16 + cl;
        #pragma unroll
        for (int r = 0; r < 4; ++r) {
            int q2 = wv * 16 + lg * 4 + r;
            if (q2 < 49) {
                int si = simgl[q2];
                if (si >= 0) o[(size_t)si * CDIM + d] = f2bf(oacc[ni][r]);
            }
        }
    }
}

// ---------------- depthwise 3x3 conv (channels-last) + BN (fp32) ----------------
__global__ __launch_bounds__(256) void conv_bn_kernel(
    const float* __restrict__ xin, const float* __restrict__ cw,
    const float* __restrict__ bn_g, const float* __restrict__ bn_b,
    const float* __restrict__ bn_m, const float* __restrict__ bn_v,
    float* __restrict__ xout)
{
    __shared__ float wsm[9 * 384];
    for (int i = threadIdx.x; i < 9 * 384; i += 256) {
        int c = i / 9, wi = i % 9;
        wsm[wi * 384 + c] = cw[i];
    }
    __syncthreads();

    int gid = blockIdx.x * 256 + threadIdx.x;
    int c4 = gid % 96;
    int t  = gid / 96;
    int w  = t % 32; t /= 32;
    int h  = t % 32;
    int b  = t / 32;
    int c0 = c4 * 4;

    float4 acc = make_float4(0.f, 0.f, 0.f, 0.f);
    #pragma unroll
    for (int dh = -1; dh <= 1; ++dh) {
        int hh = h + dh;
        if (hh < 0 || hh >= 32) continue;
        #pragma unroll
        for (int dw = -1; dw <= 1; ++dw) {
            int ww = w + dw;
            if (ww < 0 || ww >= 32) continue;
            float4 xv = *(const float4*)(xin + ((size_t)(b * 1024 + hh * 32 + ww)) * CDIM + c0);
            float4 wv = *(const float4*)&wsm[((dh + 1) * 3 + (dw + 1)) * 384 + c0];
            acc.x = fmaf(xv.x, wv.x, acc.x);
            acc.y = fmaf(xv.y, wv.y, acc.y);
            acc.z = fmaf(xv.z, wv.z, acc.z);
            acc.w = fmaf(xv.w, wv.w, acc.w);
        }
    }
    float4 o;
    float sc;
    sc = rsqrtf(bn_v[c0 + 0] + EPSF) * bn_g[c0 + 0]; o.x = (acc.x - bn_m[c0 + 0]) * sc + bn_b[c0 + 0];
    sc = rsqrtf(bn_v[c0 + 1] + EPSF) * bn_g[c0 + 1]; o.y = (acc.y - bn_m[c0 + 1]) * sc + bn_b[c0 + 1];
    sc = rsqrtf(bn_v[c0 + 2] + EPSF) * bn_g[c0 + 2]; o.z = (acc.z - bn_m[c0 + 2]) * sc + bn_b[c0 + 2];
    sc = rsqrtf(bn_v[c0 + 3] + EPSF) * bn_g[c0 + 3]; o.w = (acc.w - bn_m[c0 + 3]) * sc + bn_b[c0 + 3];
    *(float4*)(xout + (size_t)gid * 4) = o;
}

// ---------------- launch ----------------
extern "C" void kernel_launch(void* const* d_in, const int* in_sizes, int n_in,
                              void* d_out, int out_size, void* d_ws, size_t ws_size,
                              hipStream_t stream) {
    const float* x         = (const float*)d_in[0];
    const float* ln1_w     = (const float*)d_in[1];
    const float* ln1_b     = (const float*)d_in[2];
    const float* qkv_w     = (const float*)d_in[3];
    const float* qkv_b     = (const float*)d_in[4];
    const float* proj_w    = (const float*)d_in[5];
    const float* proj_b    = (const float*)d_in[6];
    const float* attn_bias = (const float*)d_in[7];
    const int*   bias_idxs = (const int*)d_in[8];
    const float* conv_w    = (const float*)d_in[9];
    const float* bn_g      = (const float*)d_in[10];
    const float* bn_b      = (const float*)d_in[11];
    const float* bn_m      = (const float*)d_in[12];
    const float* bn_v      = (const float*)d_in[13];
    const float* ln2_w     = (const float*)d_in[14];
    const float* ln2_b     = (const float*)d_in[15];
    const float* fc1_w     = (const float*)d_in[16];
    const float* fc1_b     = (const float*)d_in[17];
    const float* fc2_w     = (const float*)d_in[18];
    const float* fc2_b     = (const float*)d_in[19];
    float* out = (float*)d_out;

    // workspace with lifetime overlays (see round-3 comment)
    char* ws = (char*)d_ws;
    ushort_t* A1    = (ushort_t*)(ws + 0);              // 32768*384*2  = 25,165,824
    ushort_t* oimg  = (ushort_t*)(ws + 0);
    ushort_t* A2    = (ushort_t*)(ws + 0);
    ushort_t* qkvb  = (ushort_t*)(ws + 25165824ULL);    // 32768*1152*2 = 75,497,472
    float*    x1    = (float*)(ws + 25165824ULL);       // 32768*384*4
    ushort_t* hbuf  = (ushort_t*)(ws + 25165824ULL);    // 32768*1536*2 = 100,663,296
    ushort_t* wtqkv = (ushort_t*)(ws + 176160768ULL);   // 1152*384*2 = 884,736
    ushort_t* wtprj = (ushort_t*)(ws + 177045504ULL);   // 384*384*2  = 294,912
    ushort_t* wtfc1 = (ushort_t*)(ws + 177340416ULL);   // 1536*384*2 = 1,179,648
    ushort_t* wtfc2 = (ushort_t*)(ws + 178520064ULL);   // 384*1536*2 = 1,179,648
    ushort_t* pvec  = (ushort_t*)(ws + 179699712ULL);   // 2,304

    // 0) weights -> bf16 [N][K]
    wt_bf16_kernel<<<dim3(36, 12), 256, 0, stream>>>(qkv_w,  wtqkv, 384, 1152);
    wt_bf16_kernel<<<dim3(12, 12), 256, 0, stream>>>(proj_w, wtprj, 384, 384);
    wt_bf16_kernel<<<dim3(48, 12), 256, 0, stream>>>(fc1_w,  wtfc1, 384, 1536);
    wt_bf16_kernel<<<dim3(12, 48), 256, 0, stream>>>(fc2_w,  wtfc2, 1536, 384);
    // 1) pad-slot qkv row (bf16)
    padvec_kernel<<<5, 256, 0, stream>>>(ln1_b, qkv_w, qkv_b, pvec);
    // 2) A1 = bf16(LN1(x))
    ln_bf16_kernel<<<8192, 256, 0, stream>>>(x, ln1_w, ln1_b, A1);
    // 3) qkvb = A1 @ wtqkv^T + qkv_b (bf16 out)   nwg=2304
    gemm_bf16_kernel<0><<<dim3(9, 256), 256, 0, stream>>>(
        A1, wtqkv, qkv_b, qkvb, nullptr, N3, CDIM);
    // 4) MFMA windowed attention -> oimg bf16
    attn_kernel<<<9600, 256, 0, stream>>>(qkvb, pvec, attn_bias, bias_idxs, oimg);
    // 5) x1 = x + oimg @ wtprj^T + proj_b   nwg=768
    gemm_bf16_kernel<2><<<dim3(3, 256), 256, 0, stream>>>(
        oimg, wtprj, proj_b, x1, x, CDIM, CDIM);
    // 6) x2(=d_out) = BN(dwconv3x3(x1))
    conv_bn_kernel<<<12288, 256, 0, stream>>>(x1, conv_w, bn_g, bn_b, bn_m, bn_v, out);
    // 7) A2 = bf16(LN2(x2))
    ln_bf16_kernel<<<8192, 256, 0, stream>>>(out, ln2_w, ln2_b, A2);
    // 8) hbuf = bf16(gelu_fast(A2 @ wtfc1^T + fc1_b))   nwg=3072
    gemm_bf16_kernel<1><<<dim3(12, 256), 256, 0, stream>>>(
        A2, wtfc1, fc1_b, hbuf, nullptr, FFDIM, CDIM);
    // 9) out = x2 + hbuf @ wtfc2^T + fc2_b  (in place over d_out)   nwg=768
    gemm_bf16_kernel<2><<<dim3(3, 256), 256, 0, stream>>>(
        hbuf, wtfc2, fc2_b, out, out, CDIM, FFDIM);
}

// Round 8
// 442.818 us; speedup vs baseline: 1.1783x; 1.0229x over previous
//
#include <hip/hip_runtime.h>
#include <math.h>

#define EPSF 1e-5f

// ---- problem dims ----
#define NROW   32768   // B*H*W image tokens
#define CDIM   384
#define N3     1152
#define FFDIM  1536

typedef unsigned short ushort_t;
typedef __attribute__((ext_vector_type(8))) short short8v;   // 8 bf16 (4 VGPRs)
typedef __attribute__((ext_vector_type(4))) float f32x4;     // MFMA accumulator

// branchless tanh-form GELU: max |err| vs exact-erf gelu ~5e-4 — below the
// bf16 ulp (~0.008) the output is quantized to anyway.
__device__ __forceinline__ float gelu_fast(float x) {
    float y = 1.5957691216f * x + 0.0713548162f * (x * x * x);
    return x * __builtin_amdgcn_rcpf(1.f + __expf(-y));
}

// fp32 -> bf16 round-to-nearest-even
__device__ __forceinline__ ushort_t f2bf(float f) {
    union { float f; unsigned u; } v; v.f = f;
    unsigned r = v.u + 0x7fffu + ((v.u >> 16) & 1u);
    return (ushort_t)(r >> 16);
}

// async global->LDS, 16B per lane; LDS dest is wave-uniform base + lane*16
__device__ __forceinline__ void gload_lds16(const void* g, void* l) {
    __builtin_amdgcn_global_load_lds(
        (const __attribute__((address_space(1))) void*)g,
        (__attribute__((address_space(3))) void*)l, 16, 0, 0);
}

// ---------------- prep kernel: 4x weight transpose->bf16 + padvec ----------------
// grid 1733 x 256: [0,432) qkv_w, [432,576) proj_w, [576,1152) fc1_w,
// [1152,1728) fc2_w, [1728,1733) padvec.
__device__ __forceinline__ void wt_body(const float* __restrict__ W,
                                        ushort_t* __restrict__ Wt,
                                        int K, int N, int idx, int nbx,
                                        float (*t)[33]) {
    const int bx = idx % nbx, by = idx / nbx;
    const int c = threadIdx.x & 31, r0 = threadIdx.x >> 5;
    #pragma unroll
    for (int i = 0; i < 4; ++i) {
        int r = r0 + i * 8;
        t[r][c] = W[(size_t)(by * 32 + r) * N + bx * 32 + c];
    }
    __syncthreads();
    #pragma unroll
    for (int i = 0; i < 4; ++i) {
        int r = r0 + i * 8;
        Wt[(size_t)(bx * 32 + r) * K + by * 32 + c] = f2bf(t[c][r]);
    }
}

__global__ __launch_bounds__(256) void prep_kernel(
    const float* __restrict__ qkv_w, const float* __restrict__ proj_w,
    const float* __restrict__ fc1_w, const float* __restrict__ fc2_w,
    const float* __restrict__ ln1_b, const float* __restrict__ qkv_b,
    ushort_t* __restrict__ wtqkv, ushort_t* __restrict__ wtprj,
    ushort_t* __restrict__ wtfc1, ushort_t* __restrict__ wtfc2,
    ushort_t* __restrict__ padvec)
{
    __shared__ float t[32][33];
    const int bid = blockIdx.x;
    if (bid < 432)       wt_body(qkv_w,  wtqkv, 384, 1152, bid,        36, t);
    else if (bid < 576)  wt_body(proj_w, wtprj, 384, 384,  bid - 432,  12, t);
    else if (bid < 1152) wt_body(fc1_w,  wtfc1, 384, 1536, bid - 576,  48, t);
    else if (bid < 1728) wt_body(fc2_w,  wtfc2, 1536, 384, bid - 1152, 12, t);
    else {
        int j = (bid - 1728) * 256 + threadIdx.x;
        if (j < N3) {
            float acc = qkv_b[j];
            for (int k = 0; k < CDIM; ++k) acc = fmaf(ln1_b[k], qkv_w[k * N3 + j], acc);
            padvec[j] = f2bf(acc);
        }
    }
}

// ---------------- fused LN (stats + normalize) -> bf16 rows, one wave/row ----------------
__global__ __launch_bounds__(256) void ln_bf16_kernel(
    const float* __restrict__ src, const float* __restrict__ w,
    const float* __restrict__ b, ushort_t* __restrict__ dst)
{
    const int row  = blockIdx.x * 4 + (threadIdx.x >> 6);
    const int lane = threadIdx.x & 63;
    const float* p = src + (size_t)row * CDIM;
    float vals[6];
    float s1 = 0.f, s2 = 0.f;
    #pragma unroll
    for (int i = 0; i < 6; ++i) {
        float v = p[lane + 64 * i];
        vals[i] = v; s1 += v; s2 += v * v;
    }
    #pragma unroll
    for (int off = 32; off > 0; off >>= 1) {
        s1 += __shfl_xor(s1, off);
        s2 += __shfl_xor(s2, off);
    }
    float mu = s1 * (1.f / CDIM);
    float rs = rsqrtf(s2 * (1.f / CDIM) - mu * mu + EPSF);
    ushort_t* q = dst + (size_t)row * CDIM;
    #pragma unroll
    for (int i = 0; i < 6; ++i) {
        int k = lane + 64 * i;
        q[k] = f2bf((vals[i] - mu) * rs * w[k] + b[k]);
    }
}

// ---------------- bf16 MFMA GEMM, double-buffered 2-phase pipeline ----------------
// C = A[M][K] @ Bt[N][K]^T. 128x128 tile, BK=64, 4 waves.
// Pipeline: STAGE(next buf) -> compute(cur buf) -> __syncthreads (drains vmcnt) —
// load latency hides under ds_read+MFMA. Static buffer alternation (no runtime idx).
// LDS reads swizzled vs pre-swizzled global source (rule 21, round-6 verified).
// EPI: 0 = +bias, bf16 store (qkv)        [LDS-repack epilogue]
//      1 = +bias, gelu, bf16 store (fc1)  [LDS-repack epilogue]
//      2 = +bias, +resid, fp32 store (proj, fc2)  [direct stores]
template<int EPI, int K>
__global__ __launch_bounds__(256) void gemm_bf16_kernel(
    const ushort_t* __restrict__ A, const ushort_t* __restrict__ Bt,
    const float* __restrict__ bias, void* __restrict__ outv,
    const float* __restrict__ resid, int Nn)
{
    __shared__ __align__(16) char raw[65536];   // 2 x (16KB A + 16KB B)

    const int tid  = threadIdx.x;
    const int lane = tid & 63;
    const int wv   = tid >> 6;
    const int wm   = (wv & 1) * 64, wn = (wv >> 1) * 64;

    // T1: bijective chunked XCD swizzle (nwg % 8 == 0 for all our grids)
    const int nbx = gridDim.x;
    const int nwg = nbx * gridDim.y;
    const int id  = blockIdx.y * nbx + blockIdx.x;
    const int cpx = nwg >> 3;
    const int swz = (id & 7) * cpx + (id >> 3);
    const int bn0 = (swz % nbx) * 128;
    const int bm0 = (swz / nbx) * 128;

    // staging: wave fills rows [wv*32, +32), 8 rows per gload_lds; source column
    // pre-swizzled (inverse of read-side XOR), LDS dest linear.
    const int g_row = lane >> 3;                       // 0..7
    const int g_col = ((lane & 7) ^ g_row) * 8;        // element col (8 bf16/chunk)

    f32x4 acc[4][4] = {};

    const int cl = lane & 15;
    const int lg = lane >> 4;
    const int sx = (cl & 7) << 4;                      // read-side byte XOR

    auto stage = [&](char* base, int kt) {
        #pragma unroll
        for (int i = 0; i < 4; ++i) {
            const int r = wv * 32 + i * 8;
            gload_lds16(A  + (size_t)(bm0 + r + g_row) * K + kt + g_col, base + r * 128);
            gload_lds16(Bt + (size_t)(bn0 + r + g_row) * K + kt + g_col, base + 16384 + r * 128);
        }
    };
    auto compute = [&](const char* base) {
        const char* Ab = base;
        const char* Bb = base + 16384;
        #pragma unroll
        for (int kb = 0; kb < 2; ++kb) {
            const int cob = (kb * 64 + lg * 16) ^ sx;  // swizzled byte col
            short8v a[4], b[4];
            #pragma unroll
            for (int mi = 0; mi < 4; ++mi)
                a[mi] = *(const short8v*)(Ab + (wm + mi * 16 + cl) * 128 + cob);
            #pragma unroll
            for (int ni = 0; ni < 4; ++ni)
                b[ni] = *(const short8v*)(Bb + (wn + ni * 16 + cl) * 128 + cob);
            #pragma unroll
            for (int mi = 0; mi < 4; ++mi)
                #pragma unroll
                for (int ni = 0; ni < 4; ++ni)
                    acc[mi][ni] = __builtin_amdgcn_mfma_f32_16x16x32_bf16(
                        a[mi], b[ni], acc[mi][ni], 0, 0, 0);
        }
    };

    char* buf0 = raw;
    char* buf1 = raw + 32768;
    constexpr int NT = K / 64;        // 6 or 24, always even

    stage(buf0, 0);
    __syncthreads();                  // drain prologue
    #pragma unroll 1
    for (int t = 0; t < NT; t += 2) {
        stage(buf1, (t + 1) * 64);    // issue next-tile loads (async)
        compute(buf0);                // overlap: ds_read+MFMA while loads fly
        __syncthreads();              // drains vmcnt+lgkm, barrier
        if (t + 2 < NT) stage(buf0, (t + 2) * 64);
        compute(buf1);
        __syncthreads();
    }

    const int rq = lg * 4;

    if (EPI == 2) {
        // direct fp32 epilogue: 4B/lane, 16 consecutive cols per quarter-wave
        #pragma unroll
        for (int ni = 0; ni < 4; ++ni) {
            const int col = bn0 + wn + ni * 16 + cl;
            const float bs = bias[col];
            #pragma unroll
            for (int mi = 0; mi < 4; ++mi) {
                const int row0 = bm0 + wm + mi * 16 + rq;
                #pragma unroll
                for (int r = 0; r < 4; ++r) {
                    size_t off = (size_t)(row0 + r) * Nn + col;
                    ((float*)outv)[off] = acc[mi][ni][r] + bs + resid[off];
                }
            }
        }
    } else {
        // bf16 epilogue: repack through LDS (reuses staging region), float4-wide
        float* Cw = (float*)(raw + wv * 8704);   // per-wave [32][68] fp32
        const int ecol = cl * 4;
        const float4 bb = *(const float4*)(bias + bn0 + wn + ecol);
        #pragma unroll
        for (int half = 0; half < 2; ++half) {
            #pragma unroll
            for (int mi2 = 0; mi2 < 2; ++mi2) {
                #pragma unroll
                for (int ni = 0; ni < 4; ++ni) {
                    #pragma unroll
                    for (int r = 0; r < 4; ++r)
                        Cw[(mi2 * 16 + rq + r) * 68 + ni * 16 + cl] =
                            acc[half * 2 + mi2][ni][r];
                }
            }
            __syncthreads();
            #pragma unroll
            for (int i = 0; i < 8; ++i) {
                const int lrow = i * 4 + lg;
                const int grow = bm0 + wm + half * 32 + lrow;
                float4 v = *(const float4*)&Cw[lrow * 68 + ecol];
                v.x += bb.x; v.y += bb.y; v.z += bb.z; v.w += bb.w;
                size_t off = (size_t)grow * Nn + bn0 + wn + ecol;
                if (EPI == 1) {
                    v.x = gelu_fast(v.x); v.y = gelu_fast(v.y);
                    v.z = gelu_fast(v.z); v.w = gelu_fast(v.w);
                }
                ushort4 pk = { f2bf(v.x), f2bf(v.y), f2bf(v.z), f2bf(v.w) };
                *(ushort4*)((ushort_t*)outv + off) = pk;
            }
            __syncthreads();
        }
    }
}

// ---------------- MFMA window attention: one block per (window, head) ----------------
__global__ __launch_bounds__(256) void attn_kernel(
    const ushort_t* __restrict__ qkv, const ushort_t* __restrict__ padvec,
    const float* __restrict__ attn_bias, const int* __restrict__ bias_idxs,
    ushort_t* __restrict__ o)
{
    const int w = blockIdx.x / 12;     // window 0..799
    const int h = blockIdx.x % 12;     // head
    __shared__ ushort_t Qs[64][40];    // [token][d], 80B stride
    __shared__ ushort_t Ks[64][40];
    __shared__ ushort_t Vts[32][72];   // [d][token], 144B stride
    __shared__ ushort_t Ps[64][72];    // [query][key]
    __shared__ float    browl[49];
    __shared__ int      simgl[49];
    const int tid  = threadIdx.x;
    const int lane = tid & 63;
    const int wv   = tid >> 6;
    const int cl   = lane & 15;
    const int lg   = lane >> 4;

    if (tid < 49) {
        int b  = w / 25, wi = w % 25;
        int gh = (wi / 5) * 7 + tid / 7;
        int gw = (wi % 5) * 7 + tid % 7;
        simgl[tid] = (gh < 32 && gw < 32) ? (b * 1024 + gh * 32 + gw) : -1;
        browl[tid] = attn_bias[h * 49 + tid];
    }

    for (int e = tid; e < 64 * 12; e += 256) {
        int t = e / 12, j = e % 12;
        uint4 val = make_uint4(0u, 0u, 0u, 0u);
        if (t < 49) {
            int b  = w / 25, wi = w % 25;
            int gh = (wi / 5) * 7 + t / 7;
            int gw = (wi % 5) * 7 + t % 7;
            const ushort_t* src = (gh < 32 && gw < 32)
                ? qkv + (size_t)(b * 1024 + gh * 32 + gw) * N3 + h * 96 + j * 8
                : padvec + h * 96 + j * 8;
            val = *(const uint4*)src;
        }
        if (j < 4)      *(uint4*)&Qs[t][j * 8] = val;
        else if (j < 8) *(uint4*)&Ks[t][(j - 4) * 8] = val;
        else {
            int d0 = (j - 8) * 8;
            unsigned uu[4] = {val.x, val.y, val.z, val.w};
            #pragma unroll
            for (int ii = 0; ii < 4; ++ii) {
                Vts[d0 + 2 * ii + 0][t] = (ushort_t)(uu[ii] & 0xffffu);
                Vts[d0 + 2 * ii + 1][t] = (ushort_t)(uu[ii] >> 16);
            }
        }
    }
    __syncthreads();

    // ---- S^T = K @ Q^T ----
    const int q = wv * 16 + cl;
    short8v qf = *(const short8v*)&Qs[q][lg * 8];
    f32x4 st[4];
    #pragma unroll
    for (int mi = 0; mi < 4; ++mi) {
        short8v kf = *(const short8v*)&Ks[mi * 16 + cl][lg * 8];
        f32x4 z = {};
        st[mi] = __builtin_amdgcn_mfma_f32_16x16x32_bf16(kf, qf, z, 0, 0, 0);
    }

    // ---- bias + in-register softmax over keys ----
    float sv[4][4];
    float m = -1e30f;
    #pragma unroll
    for (int mi = 0; mi < 4; ++mi)
        #pragma unroll
        for (int r = 0; r < 4; ++r) {
            int key = mi * 16 + lg * 4 + r;
            float bb = (q < 49 && key < 49)
                     ? browl[bias_idxs[q * 49 + key]] : -1e30f;
            float s = st[mi][r] * 0.17677669529663687f + bb;
            sv[mi][r] = s;
            m = fmaxf(m, s);
        }
    m = fmaxf(m, __shfl_xor(m, 16));
    m = fmaxf(m, __shfl_xor(m, 32));
    float sum = 0.f;
    #pragma unroll
    for (int mi = 0; mi < 4; ++mi)
        #pragma unroll
        for (int r = 0; r < 4; ++r) {
            float p = __expf(sv[mi][r] - m);
            sv[mi][r] = p;
            sum += p;
        }
    sum += __shfl_xor(sum, 16);
    sum += __shfl_xor(sum, 32);
    const float inv = 1.f / sum;

    // ---- P -> LDS (wave-local rows; no barrier) ----
    #pragma unroll
    for (int mi = 0; mi < 4; ++mi) {
        uint2 pk;
        pk.x = (unsigned)f2bf(sv[mi][0] * inv) | ((unsigned)f2bf(sv[mi][1] * inv) << 16);
        pk.y = (unsigned)f2bf(sv[mi][2] * inv) | ((unsigned)f2bf(sv[mi][3] * inv) << 16);
        *(uint2*)&Ps[q][mi * 16 + lg * 4] = pk;
    }

    // ---- O = P @ V ----
    f32x4 oacc[2] = {};
    #pragma unroll
    for (int kb = 0; kb < 2; ++kb) {
        short8v pa = *(const short8v*)&Ps[q][kb * 32 + lg * 8];
        #pragma unroll
        for (int ni = 0; ni < 2; ++ni) {
            short8v vb = *(const short8v*)&Vts[ni * 16 + cl][kb * 32 + lg * 8];
            oacc[ni] = __builtin_amdgcn_mfma_f32_16x16x32_bf16(pa, vb, oacc[ni], 0, 0, 0);
        }
    }

    // ---- scatter ----
    #pragma unroll
    for (int ni = 0; ni < 2; ++ni) {
        int d = h * 32 + ni * 16 + cl;
        #pragma unroll
        for (int r = 0; r < 4; ++r) {
            int q2 = wv * 16 + lg * 4 + r;
            if (q2 < 49) {
                int si = simgl[q2];
                if (si >= 0) o[(size_t)si * CDIM + d] = f2bf(oacc[ni][r]);
            }
        }
    }
}

// ---------------- depthwise 3x3 conv (channels-last) + BN (fp32) ----------------
__global__ __launch_bounds__(256) void conv_bn_kernel(
    const float* __restrict__ xin, const float* __restrict__ cw,
    const float* __restrict__ bn_g, const float* __restrict__ bn_b,
    const float* __restrict__ bn_m, const float* __restrict__ bn_v,
    float* __restrict__ xout)
{
    __shared__ float wsm[9 * 384];
    for (int i = threadIdx.x; i < 9 * 384; i += 256) {
        int c = i / 9, wi = i % 9;
        wsm[wi * 384 + c] = cw[i];
    }
    __syncthreads();

    int gid = blockIdx.x * 256 + threadIdx.x;
    int c4 = gid % 96;
    int t  = gid / 96;
    int w  = t % 32; t /= 32;
    int h  = t % 32;
    int b  = t / 32;
    int c0 = c4 * 4;

    float4 acc = make_float4(0.f, 0.f, 0.f, 0.f);
    #pragma unroll
    for (int dh = -1; dh <= 1; ++dh) {
        int hh = h + dh;
        if (hh < 0 || hh >= 32) continue;
        #pragma unroll
        for (int dw = -1; dw <= 1; ++dw) {
            int ww = w + dw;
            if (ww < 0 || ww >= 32) continue;
            float4 xv = *(const float4*)(xin + ((size_t)(b * 1024 + hh * 32 + ww)) * CDIM + c0);
            float4 wv = *(const float4*)&wsm[((dh + 1) * 3 + (dw + 1)) * 384 + c0];
            acc.x = fmaf(xv.x, wv.x, acc.x);
            acc.y = fmaf(xv.y, wv.y, acc.y);
            acc.z = fmaf(xv.z, wv.z, acc.z);
            acc.w = fmaf(xv.w, wv.w, acc.w);
        }
    }
    float4 o;
    float sc;
    sc = rsqrtf(bn_v[c0 + 0] + EPSF) * bn_g[c0 + 0]; o.x = (acc.x - bn_m[c0 + 0]) * sc + bn_b[c0 + 0];
    sc = rsqrtf(bn_v[c0 + 1] + EPSF) * bn_g[c0 + 1]; o.y = (acc.y - bn_m[c0 + 1]) * sc + bn_b[c0 + 1];
    sc = rsqrtf(bn_v[c0 + 2] + EPSF) * bn_g[c0 + 2]; o.z = (acc.z - bn_m[c0 + 2]) * sc + bn_b[c0 + 2];
    sc = rsqrtf(bn_v[c0 + 3] + EPSF) * bn_g[c0 + 3]; o.w = (acc.w - bn_m[c0 + 3]) * sc + bn_b[c0 + 3];
    *(float4*)(xout + (size_t)gid * 4) = o;
}

// ---------------- launch ----------------
extern "C" void kernel_launch(void* const* d_in, const int* in_sizes, int n_in,
                              void* d_out, int out_size, void* d_ws, size_t ws_size,
                              hipStream_t stream) {
    const float* x         = (const float*)d_in[0];
    const float* ln1_w     = (const float*)d_in[1];
    const float* ln1_b     = (const float*)d_in[2];
    const float* qkv_w     = (const float*)d_in[3];
    const float* qkv_b     = (const float*)d_in[4];
    const float* proj_w    = (const float*)d_in[5];
    const float* proj_b    = (const float*)d_in[6];
    const float* attn_bias = (const float*)d_in[7];
    const int*   bias_idxs = (const int*)d_in[8];
    const float* conv_w    = (const float*)d_in[9];
    const float* bn_g      = (const float*)d_in[10];
    const float* bn_b      = (const float*)d_in[11];
    const float* bn_m      = (const float*)d_in[12];
    const float* bn_v      = (const float*)d_in[13];
    const float* ln2_w     = (const float*)d_in[14];
    const float* ln2_b     = (const float*)d_in[15];
    const float* fc1_w     = (const float*)d_in[16];
    const float* fc1_b     = (const float*)d_in[17];
    const float* fc2_w     = (const float*)d_in[18];
    const float* fc2_b     = (const float*)d_in[19];
    float* out = (float*)d_out;

    // workspace with lifetime overlays (see round-3 comment)
    char* ws = (char*)d_ws;
    ushort_t* A1    = (ushort_t*)(ws + 0);              // 32768*384*2  = 25,165,824
    ushort_t* oimg  = (ushort_t*)(ws + 0);
    ushort_t* A2    = (ushort_t*)(ws + 0);
    ushort_t* qkvb  = (ushort_t*)(ws + 25165824ULL);    // 32768*1152*2 = 75,497,472
    float*    x1    = (float*)(ws + 25165824ULL);       // 32768*384*4
    ushort_t* hbuf  = (ushort_t*)(ws + 25165824ULL);    // 32768*1536*2 = 100,663,296
    ushort_t* wtqkv = (ushort_t*)(ws + 176160768ULL);   // 1152*384*2 = 884,736
    ushort_t* wtprj = (ushort_t*)(ws + 177045504ULL);   // 384*384*2  = 294,912
    ushort_t* wtfc1 = (ushort_t*)(ws + 177340416ULL);   // 1536*384*2 = 1,179,648
    ushort_t* wtfc2 = (ushort_t*)(ws + 178520064ULL);   // 384*1536*2 = 1,179,648
    ushort_t* pvec  = (ushort_t*)(ws + 179699712ULL);   // 2,304

    // 0) weights -> bf16 [N][K] + padvec, one fused launch
    prep_kernel<<<1733, 256, 0, stream>>>(qkv_w, proj_w, fc1_w, fc2_w, ln1_b, qkv_b,
                                          wtqkv, wtprj, wtfc1, wtfc2, pvec);
    // 1) A1 = bf16(LN1(x))
    ln_bf16_kernel<<<8192, 256, 0, stream>>>(x, ln1_w, ln1_b, A1);
    // 2) qkvb = A1 @ wtqkv^T + qkv_b (bf16 out)   nwg=2304
    gemm_bf16_kernel<0, 384><<<dim3(9, 256), 256, 0, stream>>>(
        A1, wtqkv, qkv_b, qkvb, nullptr, N3);
    // 3) MFMA windowed attention -> oimg bf16
    attn_kernel<<<9600, 256, 0, stream>>>(qkvb, pvec, attn_bias, bias_idxs, oimg);
    // 4) x1 = x + oimg @ wtprj^T + proj_b   nwg=768
    gemm_bf16_kernel<2, 384><<<dim3(3, 256), 256, 0, stream>>>(
        oimg, wtprj, proj_b, x1, x, CDIM);
    // 5) x2(=d_out) = BN(dwconv3x3(x1))
    conv_bn_kernel<<<12288, 256, 0, stream>>>(x1, conv_w, bn_g, bn_b, bn_m, bn_v, out);
    // 6) A2 = bf16(LN2(x2))
    ln_bf16_kernel<<<8192, 256, 0, stream>>>(out, ln2_w, ln2_b, A2);
    // 7) hbuf = bf16(gelu_fast(A2 @ wtfc1^T + fc1_b))   nwg=3072
    gemm_bf16_kernel<1, 384><<<dim3(12, 256), 256, 0, stream>>>(
        A2, wtfc1, fc1_b, hbuf, nullptr, FFDIM);
    // 8) out = x2 + hbuf @ wtfc2^T + fc2_b  (in place over d_out)   nwg=768
    gemm_bf16_kernel<2, 1536><<<dim3(3, 256), 256, 0, stream>>>(
        hbuf, wtfc2, fc2_b, out, out, CDIM);
}